// Round 7
// baseline (172.273 us; speedup 1.0000x reference)
//
#include <hip/hip_runtime.h>
#include <stdint.h>

#define TABLE_BITS 21
#define TABLE_SIZE (1u << TABLE_BITS)      // 2,097,152 entries > max key 1,999,999
#define TABLE_MASK (TABLE_SIZE - 1u)
#define BLOCK 256
#define EPT 4
#define CHUNK (BLOCK * EPT)                // 1024 elements/block (flags/out)
#define EPT2 16
#define CHUNK2 (BLOCK * EPT2)              // 4096 elements/block (hist/scatter)
#define NB 256                             // key-range buckets
#define BSHIFT (TABLE_BITS - 8)            // 8192 keys per bucket
#define KPB (1 << BSHIFT)
#define KLOW_MASK (KPB - 1)
#define INF_PAT 0x7f7f7f7f
#define BJ_INVALID 0xFFFFFFFFu
#define RANK_BIT 0x40000000                // fallback path only
#define RANK_MASK 0x3FFFFFFF

// ---- block exclusive scan (NT threads) ----
template<int NT>
__device__ __forceinline__ int blk_excl_scan(int v, int tid, int* total) {
    constexpr int NW = NT / 64;
    int lane = tid & 63, w = tid >> 6;
    int inc = v;
    #pragma unroll
    for (int off = 1; off < 64; off <<= 1) {
        int u = __shfl_up(inc, off, 64);
        if (lane >= off) inc += u;
    }
    __shared__ int part[NW];
    if (lane == 63) part[w] = inc;
    __syncthreads();
    if (tid < NW) {
        int p = part[tid];
        #pragma unroll
        for (int off = 1; off < NW; off <<= 1) {
            int u = __shfl_up(p, off, 64);
            if (tid >= off) p += u;
        }
        part[tid] = p;
    }
    __syncthreads();
    int excl = ((w == 0) ? 0 : part[w - 1]) + inc - v;
    int tot = part[NW - 1];
    __syncthreads();
    if (total) *total = tot;
    return excl;
}

// ---------- A: per-block 256-bucket histogram (LDS atomics only) ----------
__global__ __launch_bounds__(BLOCK) void k_hist(const int* __restrict__ x, int n,
                                                unsigned* __restrict__ hist) {
    __shared__ unsigned cnt[NB];
    int tid = threadIdx.x;
    cnt[tid] = 0;
    __syncthreads();
    int e0 = blockIdx.x * CHUNK2;
    #pragma unroll
    for (int k = 0; k < EPT2 / 4; ++k) {
        int idx = e0 + k * (BLOCK * 4) + tid * 4;
        if (idx + 4 <= n) {
            int4 v = *reinterpret_cast<const int4*>(x + idx);
            atomicAdd(&cnt[((unsigned)v.x & TABLE_MASK) >> BSHIFT], 1u);
            atomicAdd(&cnt[((unsigned)v.y & TABLE_MASK) >> BSHIFT], 1u);
            atomicAdd(&cnt[((unsigned)v.z & TABLE_MASK) >> BSHIFT], 1u);
            atomicAdd(&cnt[((unsigned)v.w & TABLE_MASK) >> BSHIFT], 1u);
        } else {
            for (int i = idx; i < n; ++i)
                atomicAdd(&cnt[((unsigned)x[i] & TABLE_MASK) >> BSHIFT], 1u);
        }
    }
    __syncthreads();
    hist[(size_t)blockIdx.x * NB + tid] = cnt[tid];
}

// ---------- B: per-bucket exclusive scan over blocks (in place) ----------
__global__ __launch_bounds__(256) void k_colscan(unsigned* __restrict__ hist, int SB2,
                                                 unsigned* __restrict__ bucketTot) {
    int j = blockIdx.x, tid = threadIdx.x;
    unsigned carry = 0;
    for (int b0 = 0; b0 < SB2; b0 += 256) {
        int b = b0 + tid;
        int v = (b < SB2) ? (int)hist[(size_t)b * NB + j] : 0;
        int tot;
        int excl = blk_excl_scan<256>(v, tid, &tot);
        if (b < SB2) hist[(size_t)b * NB + j] = carry + (unsigned)excl;
        carry += (unsigned)tot;
    }
    if (tid == 0) bucketTot[j] = carry;
}

// ---------- B2: exclusive scan of bucket totals ----------
__global__ __launch_bounds__(256) void k_bucketbase(const unsigned* __restrict__ bucketTot,
                                                    unsigned* __restrict__ bucketBase) {
    int tid = threadIdx.x;
    int v = (int)bucketTot[tid];
    int tot;
    int excl = blk_excl_scan<256>(v, tid, &tot);
    bucketBase[tid] = (unsigned)excl;
    if (tid == 255) bucketBase[256] = (unsigned)(excl + v);
}

// ---------- C: LDS-staged scatter -> split 6B pairs grouped by bucket ----------
__global__ __launch_bounds__(BLOCK) void k_scatter(const int* __restrict__ x, int n,
                                                   const unsigned* __restrict__ hist,
                                                   const unsigned* __restrict__ bucketBase,
                                                   unsigned* __restrict__ posArr,
                                                   unsigned short* __restrict__ klArr) {
    __shared__ unsigned cnt[NB];
    __shared__ unsigned lbase[NB + 1];
    __shared__ unsigned sbase[NB];
    __shared__ unsigned lpos[CHUNK2];              // 16 KB
    __shared__ unsigned short lkl[CHUNK2];         // 8 KB
    int tid = threadIdx.x;
    cnt[tid] = 0;
    sbase[tid] = bucketBase[tid] + hist[(size_t)blockIdx.x * NB + tid];
    __syncthreads();

    unsigned bjs[EPT2], kls[EPT2], los[EPT2];
    int e0 = blockIdx.x * CHUNK2;
    // pass 1: bucket ids + local offsets
    #pragma unroll
    for (int k = 0; k < EPT2 / 4; ++k) {
        int idx = e0 + k * (BLOCK * 4) + tid * 4;
        if (idx + 4 <= n) {
            int4 v = *reinterpret_cast<const int4*>(x + idx);
            unsigned kk[4] = {(unsigned)v.x & TABLE_MASK, (unsigned)v.y & TABLE_MASK,
                              (unsigned)v.z & TABLE_MASK, (unsigned)v.w & TABLE_MASK};
            #pragma unroll
            for (int j = 0; j < 4; ++j) {
                int e = k * 4 + j;
                bjs[e] = kk[j] >> BSHIFT;
                kls[e] = kk[j] & KLOW_MASK;
                los[e] = atomicAdd(&cnt[bjs[e]], 1u);
            }
        } else {
            #pragma unroll
            for (int j = 0; j < 4; ++j) {
                int e = k * 4 + j;
                int i = idx + j;
                if (i < n) {
                    unsigned kv = (unsigned)x[i] & TABLE_MASK;
                    bjs[e] = kv >> BSHIFT;
                    kls[e] = kv & KLOW_MASK;
                    los[e] = atomicAdd(&cnt[bjs[e]], 1u);
                } else {
                    bjs[e] = BJ_INVALID;
                }
            }
        }
    }
    __syncthreads();
    // scan local counts -> local bucket bases
    {
        int v = (int)cnt[tid];
        int tot;
        int ex = blk_excl_scan<256>(v, tid, &tot);
        lbase[tid] = (unsigned)ex;
        if (tid == 255) lbase[256] = (unsigned)(ex + v);
    }
    __syncthreads();
    // pass 2: place into LDS ordered by bucket
    #pragma unroll
    for (int k = 0; k < EPT2 / 4; ++k) {
        #pragma unroll
        for (int j = 0; j < 4; ++j) {
            int e = k * 4 + j;
            if (bjs[e] != BJ_INVALID) {
                unsigned dst = lbase[bjs[e]] + los[e];
                lpos[dst] = (unsigned)(e0 + k * (BLOCK * 4) + tid * 4 + j);
                lkl[dst]  = (unsigned short)kls[e];
            }
        }
    }
    __syncthreads();
    // flush: wave per bucket, contiguous bursts
    int wv = tid >> 6, ln = tid & 63;
    for (int j = wv; j < NB; j += BLOCK / 64) {
        unsigned ls = lbase[j], len = lbase[j + 1] - ls, gs = sbase[j];
        for (unsigned i = ln; i < len; i += 64) {
            posArr[gs + i] = lpos[ls + i];
            klArr[gs + i]  = lkl[ls + i];
        }
    }
}

// ---------- D: per-bucket first-idx in LDS; table (=first idx) + flag bytes ----------
__global__ __launch_bounds__(512) void k_bucket_min(const unsigned* __restrict__ posArr,
                                                    const unsigned short* __restrict__ klArr,
                                                    const unsigned* __restrict__ bucketBase,
                                                    int* __restrict__ table,
                                                    unsigned char* __restrict__ flag) {
    __shared__ int fi[KPB];                 // 32 KB
    int j = blockIdx.x, tid = threadIdx.x;
    for (int k = tid; k < KPB; k += 512) fi[k] = INF_PAT;
    __syncthreads();
    unsigned s = bucketBase[j], e = bucketBase[j + 1];
    for (unsigned idx = s + tid; idx < e; idx += 512)
        atomicMin(&fi[klArr[idx]], (int)posArr[idx]);
    __syncthreads();
    int* dst = table + (size_t)j * KPB;
    for (int k = tid; k < KPB; k += 512) dst[k] = fi[k];
    // flag bytes: every position written exactly once (L2-hot re-read)
    for (unsigned idx = s + tid; idx < e; idx += 512) {
        unsigned pos = posArr[idx];
        flag[pos] = (unsigned char)(fi[klArr[idx]] == (int)pos);
    }
}

// ---------- E: flag bytes -> consecutive-bit per-block bitmask + blockSums ----------
__global__ __launch_bounds__(BLOCK) void k_flags(const unsigned char* __restrict__ flag, int n,
                                                 int* __restrict__ blockSums,
                                                 unsigned long long* __restrict__ bitmask) {
    __shared__ unsigned long long words[16];       // 1024 bits, consecutive order
    int tid = threadIdx.x;
    int lane = tid & 63, w = tid >> 6;
    if (tid < 16) words[tid] = 0ull;
    __syncthreads();
    int base = blockIdx.x * CHUNK + tid * EPT;
    unsigned nib = 0;
    if (base + EPT <= n) {
        uchar4 f = *reinterpret_cast<const uchar4*>(flag + base);
        nib = (unsigned)f.x | ((unsigned)f.y << 1) | ((unsigned)f.z << 2) | ((unsigned)f.w << 3);
    } else {
        #pragma unroll
        for (int j = 0; j < EPT; ++j)
            if (base + j < n) nib |= (unsigned)flag[base + j] << j;
    }
    if (nib)
        atomicOr(&words[tid >> 4], (unsigned long long)nib << ((tid * 4) & 63));
    int cnt = __popc(nib);
    for (int off = 32; off > 0; off >>= 1)
        cnt += __shfl_down(cnt, off, 64);
    __shared__ int ws[BLOCK / 64];
    if (lane == 0) ws[w] = cnt;
    __syncthreads();
    if (tid < 16) bitmask[(size_t)blockIdx.x * 16 + tid] = words[tid];
    if (tid == 0) {
        int s = 0;
        #pragma unroll
        for (int q = 0; q < BLOCK / 64; ++q) s += ws[q];
        blockSums[blockIdx.x] = s;
    }
}

// ---------- F: single-block exclusive scan of blockSums ----------
__global__ __launch_bounds__(1024) void k_scan(int* __restrict__ sums, int B) {
    int tid = threadIdx.x;
    int carry = 0;
    for (int b0 = 0; b0 < B; b0 += 1024) {
        int b = b0 + tid;
        int v = (b < B) ? sums[b] : 0;
        int tot;
        int excl = blk_excl_scan<1024>(v, tid, &tot);
        if (b < B) sums[b] = carry + excl;
        carry += tot;
    }
}

// ---------- G: per-bucket rank assignment; writes FINAL ids into table ----------
__global__ __launch_bounds__(512) void k_rank_bucket(const unsigned* __restrict__ posArr,
                                                     const unsigned short* __restrict__ klArr,
                                                     const unsigned* __restrict__ bucketBase,
                                                     const int* __restrict__ blockSums,
                                                     const unsigned long long* __restrict__ bitmask,
                                                     const int* __restrict__ mtp,
                                                     int* __restrict__ table) {
    __shared__ int fi[KPB];                 // 32 KB
    __shared__ unsigned idv[KPB];           // 32 KB
    int j = blockIdx.x, tid = threadIdx.x;
    int* slice = table + (size_t)j * KPB;
    for (int k = tid; k < KPB; k += 512) fi[k] = slice[k];
    __syncthreads();
    int mt = mtp[0];
    unsigned s = bucketBase[j], e = bucketBase[j + 1];
    for (unsigned idx = s + tid; idx < e; idx += 512) {
        unsigned pos = posArr[idx];
        unsigned kl = klArr[idx];
        if (fi[kl] == (int)pos) {
            const unsigned long long* bm = bitmask + (size_t)(pos >> 10) * 16;
            unsigned bit = pos & 1023u;
            unsigned w0 = bit >> 6, b0 = bit & 63u;
            int r = blockSums[pos >> 10];
            for (unsigned w = 0; w < w0; ++w) r += __popcll(bm[w]);
            r += __popcll(bm[w0] & ((1ull << b0) - 1ull));
            idv[kl] = (r < mt) ? (unsigned)(r + 1) : 0u;
        }
    }
    __syncthreads();
    for (int k = tid; k < KPB; k += 512)
        slice[k] = (fi[k] != INF_PAT) ? (int)idv[k] : 0;
}

// ---------- H: pure gather of finalized ids ----------
__global__ __launch_bounds__(BLOCK) void k_out(const int* __restrict__ x, int n,
                                               const int* __restrict__ table,
                                               int* __restrict__ out) {
    int base = (blockIdx.x * BLOCK + threadIdx.x) * EPT;
    if (base + EPT <= n) {
        int4 v = *reinterpret_cast<const int4*>(x + base);
        int4 o;
        o.x = table[(unsigned)v.x & TABLE_MASK];
        o.y = table[(unsigned)v.y & TABLE_MASK];
        o.z = table[(unsigned)v.z & TABLE_MASK];
        o.w = table[(unsigned)v.w & TABLE_MASK];
        *reinterpret_cast<int4*>(out + base) = o;
    } else {
        for (int i = base; i < n; ++i)
            out[i] = table[(unsigned)x[i] & TABLE_MASK];
    }
}

// ---------- fallback path (small ws): device-scope atomics ----------
__global__ __launch_bounds__(BLOCK) void k_first_idx(const int* __restrict__ x, int n,
                                                     int* __restrict__ table) {
    int base = (blockIdx.x * BLOCK + threadIdx.x) * EPT;
    for (int i = base; i < min(base + EPT, n); ++i)
        atomicMin(&table[(unsigned)x[i] & TABLE_MASK], i);
}
__global__ __launch_bounds__(BLOCK) void k_rank_fb(const int* __restrict__ x, int n,
                                                   int* __restrict__ table,
                                                   int* __restrict__ blockSums) {
    int tid = threadIdx.x;
    int base = blockIdx.x * CHUNK + tid * EPT;
    int flags[EPT];
    int cnt = 0;
    #pragma unroll
    for (int j = 0; j < EPT; ++j) {
        flags[j] = 0;
        if (base + j < n)
            flags[j] = (table[(unsigned)x[base + j] & TABLE_MASK] == base + j);
        cnt += flags[j];
    }
    int tot;
    int r = blockSums[blockIdx.x] + blk_excl_scan<BLOCK>(cnt, tid, &tot);
    #pragma unroll
    for (int j = 0; j < EPT; ++j)
        if (flags[j]) table[(unsigned)x[base + j] & TABLE_MASK] = (r++) | RANK_BIT;
}
__global__ __launch_bounds__(BLOCK) void k_count_fb(const int* __restrict__ x, int n,
                                                    const int* __restrict__ table,
                                                    int* __restrict__ blockSums) {
    int tid = threadIdx.x;
    int base = blockIdx.x * CHUNK + tid * EPT;
    int cnt = 0;
    #pragma unroll
    for (int j = 0; j < EPT; ++j)
        if (base + j < n)
            cnt += (table[(unsigned)x[base + j] & TABLE_MASK] == base + j);
    int tot;
    blk_excl_scan<BLOCK>(cnt, tid, &tot);
    if (tid == 0) blockSums[blockIdx.x] = tot;
}
__global__ __launch_bounds__(BLOCK) void k_out_fb(const int* __restrict__ x, int n,
                                                  const int* __restrict__ table,
                                                  const int* __restrict__ mtp,
                                                  int* __restrict__ out) {
    int mt = mtp[0];
    int base = (blockIdx.x * BLOCK + threadIdx.x) * EPT;
    for (int i = base; i < min(base + EPT, n); ++i) {
        int r = table[(unsigned)x[i] & TABLE_MASK] & RANK_MASK;
        out[i] = (r < mt) ? r + 1 : 0;
    }
}

extern "C" void kernel_launch(void* const* d_in, const int* in_sizes, int n_in,
                              void* d_out, int out_size, void* d_ws, size_t ws_size,
                              hipStream_t stream) {
    const int* x   = (const int*)d_in[0];
    const int* mtp = (const int*)d_in[1];
    int n = in_sizes[0];
    int* out = (int*)d_out;

    int SB  = (n + CHUNK  - 1) / CHUNK;    // 1024-granularity blocks
    int SB2 = (n + CHUNK2 - 1) / CHUNK2;   // 4096-granularity blocks

    auto align16 = [](size_t v) { return (v + 15) & ~(size_t)15; };
    size_t off = 0;
    int* table = (int*)d_ws;                                      off = align16(off + (size_t)TABLE_SIZE * 4);
    unsigned* posArr = (unsigned*)((char*)d_ws + off);            off = align16(off + (size_t)n * 4);
    unsigned short* klArr = (unsigned short*)((char*)d_ws + off); off = align16(off + (size_t)n * 2);
    unsigned char* flag = (unsigned char*)((char*)d_ws + off);    off = align16(off + (size_t)n);
    unsigned* hist = (unsigned*)((char*)d_ws + off);              off = align16(off + (size_t)SB2 * NB * 4);
    unsigned* bucketTot = (unsigned*)((char*)d_ws + off);         off = align16(off + (size_t)NB * 4);
    unsigned* bucketBase = (unsigned*)((char*)d_ws + off);        off = align16(off + (size_t)(NB + 1) * 4);
    int* blockSums = (int*)((char*)d_ws + off);                   off = align16(off + (size_t)SB * 4);
    unsigned long long* bitmask = (unsigned long long*)((char*)d_ws + off);
    off = align16(off + (size_t)SB * 16 * 8);

    if (ws_size >= off) {
        k_hist       <<<SB2, BLOCK, 0, stream>>>(x, n, hist);
        k_colscan    <<<NB,  256,   0, stream>>>(hist, SB2, bucketTot);
        k_bucketbase <<<1,   256,   0, stream>>>(bucketTot, bucketBase);
        k_scatter    <<<SB2, BLOCK, 0, stream>>>(x, n, hist, bucketBase, posArr, klArr);
        k_bucket_min <<<NB,  512,   0, stream>>>(posArr, klArr, bucketBase, table, flag);
        k_flags      <<<SB,  BLOCK, 0, stream>>>(flag, n, blockSums, bitmask);
        k_scan       <<<1,   1024,  0, stream>>>(blockSums, SB);
        k_rank_bucket<<<NB,  512,   0, stream>>>(posArr, klArr, bucketBase, blockSums,
                                                 bitmask, mtp, table);
        k_out        <<<SB,  BLOCK, 0, stream>>>(x, n, table, out);
    } else {
        // minimal-footprint fallback
        size_t foff = align16((size_t)TABLE_SIZE * 4);
        int* bs = (int*)((char*)d_ws + foff);
        hipMemsetAsync(table, 0x7F, (size_t)TABLE_SIZE * 4, stream);
        k_first_idx<<<SB, BLOCK, 0, stream>>>(x, n, table);
        k_count_fb <<<SB, BLOCK, 0, stream>>>(x, n, table, bs);
        k_scan     <<<1, 1024, 0, stream>>>(bs, SB);
        k_rank_fb  <<<SB, BLOCK, 0, stream>>>(x, n, table, bs);
        k_out_fb   <<<SB, BLOCK, 0, stream>>>(x, n, table, mtp, out);
    }
}

// Round 8
// 133.774 us; speedup vs baseline: 1.2878x; 1.2878x over previous
//
#include <hip/hip_runtime.h>
#include <stdint.h>

#define TABLE_BITS 21
#define TABLE_SIZE (1u << TABLE_BITS)      // 2,097,152 entries > max key 1,999,999
#define TABLE_MASK (TABLE_SIZE - 1u)
#define BLOCK 256
#define EPT 4
#define CHUNK (BLOCK * EPT)                // 1024 elements/block (flags/rank/out)
#define EPT2 16
#define CHUNK2 (BLOCK * EPT2)              // 4096 elements/block (hist/scatter)
#define RANK_BIT 0x40000000
#define RANK_MASK 0x3FFFFFFF
#define NB 256                             // key-range buckets
#define BSHIFT (TABLE_BITS - 8)            // 8192 keys per bucket
#define KPB (1 << BSHIFT)
#define KLOW_MASK (KPB - 1)
#define INF_PAT 0x7f7f7f7f
#define BJ_INVALID 0xFFFFFFFFu

// ---- block exclusive scan (NT threads) ----
template<int NT>
__device__ __forceinline__ int blk_excl_scan(int v, int tid, int* total) {
    constexpr int NW = NT / 64;
    int lane = tid & 63, w = tid >> 6;
    int inc = v;
    #pragma unroll
    for (int off = 1; off < 64; off <<= 1) {
        int u = __shfl_up(inc, off, 64);
        if (lane >= off) inc += u;
    }
    __shared__ int part[NW];
    if (lane == 63) part[w] = inc;
    __syncthreads();
    if (tid < NW) {
        int p = part[tid];
        #pragma unroll
        for (int off = 1; off < NW; off <<= 1) {
            int u = __shfl_up(p, off, 64);
            if (tid >= off) p += u;
        }
        part[tid] = p;
    }
    __syncthreads();
    int excl = ((w == 0) ? 0 : part[w - 1]) + inc - v;
    int tot = part[NW - 1];
    __syncthreads();
    if (total) *total = tot;
    return excl;
}

// ---------- A: per-block 256-bucket histogram (LDS atomics only) ----------
__global__ __launch_bounds__(BLOCK) void k_hist(const int* __restrict__ x, int n,
                                                unsigned* __restrict__ hist) {
    __shared__ unsigned cnt[NB];
    int tid = threadIdx.x;
    cnt[tid] = 0;
    __syncthreads();
    int e0 = blockIdx.x * CHUNK2;
    #pragma unroll
    for (int k = 0; k < EPT2 / 4; ++k) {
        int idx = e0 + k * (BLOCK * 4) + tid * 4;
        if (idx + 4 <= n) {
            int4 v = *reinterpret_cast<const int4*>(x + idx);
            atomicAdd(&cnt[((unsigned)v.x & TABLE_MASK) >> BSHIFT], 1u);
            atomicAdd(&cnt[((unsigned)v.y & TABLE_MASK) >> BSHIFT], 1u);
            atomicAdd(&cnt[((unsigned)v.z & TABLE_MASK) >> BSHIFT], 1u);
            atomicAdd(&cnt[((unsigned)v.w & TABLE_MASK) >> BSHIFT], 1u);
        } else {
            for (int i = idx; i < n; ++i)
                atomicAdd(&cnt[((unsigned)x[i] & TABLE_MASK) >> BSHIFT], 1u);
        }
    }
    __syncthreads();
    hist[(size_t)blockIdx.x * NB + tid] = cnt[tid];
}

// ---------- B: per-bucket exclusive scan over blocks (in place) ----------
__global__ __launch_bounds__(256) void k_colscan(unsigned* __restrict__ hist, int SB2,
                                                 unsigned* __restrict__ bucketTot) {
    int j = blockIdx.x, tid = threadIdx.x;
    unsigned carry = 0;
    for (int b0 = 0; b0 < SB2; b0 += 256) {
        int b = b0 + tid;
        int v = (b < SB2) ? (int)hist[(size_t)b * NB + j] : 0;
        int tot;
        int excl = blk_excl_scan<256>(v, tid, &tot);
        if (b < SB2) hist[(size_t)b * NB + j] = carry + (unsigned)excl;
        carry += (unsigned)tot;
    }
    if (tid == 0) bucketTot[j] = carry;
}

// ---------- B2: exclusive scan of bucket totals ----------
__global__ __launch_bounds__(256) void k_bucketbase(const unsigned* __restrict__ bucketTot,
                                                    unsigned* __restrict__ bucketBase) {
    int tid = threadIdx.x;
    int v = (int)bucketTot[tid];
    int tot;
    int excl = blk_excl_scan<256>(v, tid, &tot);
    bucketBase[tid] = (unsigned)excl;
    if (tid == 255) bucketBase[256] = (unsigned)(excl + v);
}

// ---------- C: LDS-staged scatter -> split 6B pairs grouped by bucket ----------
__global__ __launch_bounds__(BLOCK) void k_scatter(const int* __restrict__ x, int n,
                                                   const unsigned* __restrict__ hist,
                                                   const unsigned* __restrict__ bucketBase,
                                                   unsigned* __restrict__ posArr,
                                                   unsigned short* __restrict__ klArr) {
    __shared__ unsigned cnt[NB];
    __shared__ unsigned lbase[NB + 1];
    __shared__ unsigned sbase[NB];
    __shared__ unsigned lpos[CHUNK2];              // 16 KB
    __shared__ unsigned short lkl[CHUNK2];         // 8 KB
    int tid = threadIdx.x;
    cnt[tid] = 0;
    sbase[tid] = bucketBase[tid] + hist[(size_t)blockIdx.x * NB + tid];
    __syncthreads();

    unsigned bjs[EPT2], kls[EPT2], los[EPT2];
    int e0 = blockIdx.x * CHUNK2;
    // pass 1: bucket ids + local offsets
    #pragma unroll
    for (int k = 0; k < EPT2 / 4; ++k) {
        int idx = e0 + k * (BLOCK * 4) + tid * 4;
        if (idx + 4 <= n) {
            int4 v = *reinterpret_cast<const int4*>(x + idx);
            unsigned kk[4] = {(unsigned)v.x & TABLE_MASK, (unsigned)v.y & TABLE_MASK,
                              (unsigned)v.z & TABLE_MASK, (unsigned)v.w & TABLE_MASK};
            #pragma unroll
            for (int j = 0; j < 4; ++j) {
                int e = k * 4 + j;
                bjs[e] = kk[j] >> BSHIFT;
                kls[e] = kk[j] & KLOW_MASK;
                los[e] = atomicAdd(&cnt[bjs[e]], 1u);
            }
        } else {
            #pragma unroll
            for (int j = 0; j < 4; ++j) {
                int e = k * 4 + j;
                int i = idx + j;
                if (i < n) {
                    unsigned kv = (unsigned)x[i] & TABLE_MASK;
                    bjs[e] = kv >> BSHIFT;
                    kls[e] = kv & KLOW_MASK;
                    los[e] = atomicAdd(&cnt[bjs[e]], 1u);
                } else {
                    bjs[e] = BJ_INVALID;
                }
            }
        }
    }
    __syncthreads();
    // scan local counts -> local bucket bases
    {
        int v = (int)cnt[tid];
        int tot;
        int ex = blk_excl_scan<256>(v, tid, &tot);
        lbase[tid] = (unsigned)ex;
        if (tid == 255) lbase[256] = (unsigned)(ex + v);
    }
    __syncthreads();
    // pass 2: place into LDS ordered by bucket
    #pragma unroll
    for (int k = 0; k < EPT2 / 4; ++k) {
        #pragma unroll
        for (int j = 0; j < 4; ++j) {
            int e = k * 4 + j;
            if (bjs[e] != BJ_INVALID) {
                unsigned dst = lbase[bjs[e]] + los[e];
                lpos[dst] = (unsigned)(e0 + k * (BLOCK * 4) + tid * 4 + j);
                lkl[dst]  = (unsigned short)kls[e];
            }
        }
    }
    __syncthreads();
    // flush: wave per bucket, contiguous bursts
    int wv = tid >> 6, ln = tid & 63;
    for (int j = wv; j < NB; j += BLOCK / 64) {
        unsigned ls = lbase[j], len = lbase[j + 1] - ls, gs = sbase[j];
        for (unsigned i = ln; i < len; i += 64) {
            posArr[gs + i] = lpos[ls + i];
            klArr[gs + i]  = lkl[ls + i];
        }
    }
}

// ---------- D: per-bucket first-idx in LDS; coalesced table write + flag bytes ----------
__global__ __launch_bounds__(512) void k_bucket_min(const unsigned* __restrict__ posArr,
                                                    const unsigned short* __restrict__ klArr,
                                                    const unsigned* __restrict__ bucketBase,
                                                    int* __restrict__ table,
                                                    unsigned char* __restrict__ flag) {
    __shared__ int fi[KPB];                 // 32 KB
    int j = blockIdx.x, tid = threadIdx.x;
    for (int k = tid; k < KPB; k += 512) fi[k] = INF_PAT;
    __syncthreads();
    unsigned s = bucketBase[j], e = bucketBase[j + 1];
    for (unsigned idx = s + tid; idx < e; idx += 512)
        atomicMin(&fi[klArr[idx]], (int)posArr[idx]);
    __syncthreads();
    int* dst = table + (size_t)j * KPB;
    for (int k = tid; k < KPB; k += 512) dst[k] = fi[k];
    // flag bytes: every position written exactly once (L2-hot re-read)
    for (unsigned idx = s + tid; idx < e; idx += 512) {
        unsigned pos = posArr[idx];
        flag[pos] = (unsigned char)(fi[klArr[idx]] == (int)pos);
    }
}

// ---------- E: sequential flag bytes -> ballot bitmask + blockSums ----------
__global__ __launch_bounds__(BLOCK) void k_flags(const unsigned char* __restrict__ flag, int n,
                                                 int* __restrict__ blockSums,
                                                 unsigned long long* __restrict__ bitmask) {
    int tid = threadIdx.x;
    int lane = tid & 63, w = tid >> 6;
    int base = blockIdx.x * CHUNK + tid * EPT;
    int flags[EPT];
    if (base + EPT <= n) {
        uchar4 f = *reinterpret_cast<const uchar4*>(flag + base);
        flags[0] = f.x; flags[1] = f.y; flags[2] = f.z; flags[3] = f.w;
    } else {
        #pragma unroll
        for (int j = 0; j < EPT; ++j)
            flags[j] = (base + j < n) ? flag[base + j] : 0;
    }
    int cnt = 0;
    #pragma unroll
    for (int j = 0; j < EPT; ++j) {
        unsigned long long mj = __ballot(flags[j]);
        if (lane == 0) bitmask[((size_t)blockIdx.x * (BLOCK / 64) + w) * EPT + j] = mj;
        cnt += flags[j];
    }
    for (int off = 32; off > 0; off >>= 1)
        cnt += __shfl_down(cnt, off, 64);
    __shared__ int ws[BLOCK / 64];
    if (lane == 0) ws[w] = cnt;
    __syncthreads();
    if (tid == 0) {
        int s = 0;
        #pragma unroll
        for (int q = 0; q < BLOCK / 64; ++q) s += ws[q];
        blockSums[blockIdx.x] = s;
    }
}

// ---------- F: single-block scan of blockSums ----------
__global__ __launch_bounds__(1024) void k_scan(int* __restrict__ sums, int B) {
    int tid = threadIdx.x;
    int carry = 0;
    for (int b0 = 0; b0 < B; b0 += 1024) {
        int b = b0 + tid;
        int v = (b < B) ? sums[b] : 0;
        int tot;
        int excl = blk_excl_scan<1024>(v, tid, &tot);
        if (b < B) sums[b] = carry + excl;
        carry += tot;
    }
}

// ---------- G: assign ranks using the bitmask ----------
__global__ __launch_bounds__(BLOCK) void k_rank(const int* __restrict__ x, int n,
                                                int* __restrict__ table,
                                                const int* __restrict__ blockSums,
                                                const unsigned long long* __restrict__ bitmask) {
    int tid = threadIdx.x;
    int lane = tid & 63, w = tid >> 6;
    int base = blockIdx.x * CHUNK + tid * EPT;
    const unsigned long long* bm = bitmask + ((size_t)blockIdx.x * (BLOCK / 64) + w) * EPT;
    int flags[EPT];
    int cnt = 0;
    #pragma unroll
    for (int j = 0; j < EPT; ++j) {
        flags[j] = (int)((bm[j] >> lane) & 1ull);
        cnt += flags[j];
    }
    __shared__ int lds[BLOCK];
    lds[tid] = cnt;
    __syncthreads();
    for (int off = 1; off < BLOCK; off <<= 1) {
        int t = (tid >= off) ? lds[tid - off] : 0;
        __syncthreads();
        lds[tid] += t;
        __syncthreads();
    }
    int r = blockSums[blockIdx.x] + lds[tid] - cnt;
    if (cnt) {
        if (base + EPT <= n) {
            int4 v = *reinterpret_cast<const int4*>(x + base);
            if (flags[0]) table[(unsigned)v.x & TABLE_MASK] = (r++) | RANK_BIT;
            if (flags[1]) table[(unsigned)v.y & TABLE_MASK] = (r++) | RANK_BIT;
            if (flags[2]) table[(unsigned)v.z & TABLE_MASK] = (r++) | RANK_BIT;
            if (flags[3]) table[(unsigned)v.w & TABLE_MASK] = (r++) | RANK_BIT;
        } else {
            #pragma unroll
            for (int j = 0; j < EPT; ++j)
                if (flags[j]) table[(unsigned)x[base + j] & TABLE_MASK] = (r++) | RANK_BIT;
        }
    }
}

// ---------- H: gather rank, apply max_tokens cutoff ----------
__global__ __launch_bounds__(BLOCK) void k_out(const int* __restrict__ x, int n,
                                               const int* __restrict__ table,
                                               const int* __restrict__ mtp,
                                               int* __restrict__ out) {
    int mt = mtp[0];
    int base = (blockIdx.x * BLOCK + threadIdx.x) * EPT;
    if (base + EPT <= n) {
        int4 v = *reinterpret_cast<const int4*>(x + base);
        int4 o;
        int r;
        r = table[(unsigned)v.x & TABLE_MASK] & RANK_MASK; o.x = (r < mt) ? r + 1 : 0;
        r = table[(unsigned)v.y & TABLE_MASK] & RANK_MASK; o.y = (r < mt) ? r + 1 : 0;
        r = table[(unsigned)v.z & TABLE_MASK] & RANK_MASK; o.z = (r < mt) ? r + 1 : 0;
        r = table[(unsigned)v.w & TABLE_MASK] & RANK_MASK; o.w = (r < mt) ? r + 1 : 0;
        *reinterpret_cast<int4*>(out + base) = o;
    } else {
        for (int i = base; i < n; ++i) {
            int r = table[(unsigned)x[i] & TABLE_MASK] & RANK_MASK;
            out[i] = (r < mt) ? r + 1 : 0;
        }
    }
}

// ---------- fallback path (small ws): device-scope atomics ----------
__global__ __launch_bounds__(BLOCK) void k_first_idx(const int* __restrict__ x, int n,
                                                     int* __restrict__ table) {
    int base = (blockIdx.x * BLOCK + threadIdx.x) * EPT;
    for (int i = base; i < min(base + EPT, n); ++i)
        atomicMin(&table[(unsigned)x[i] & TABLE_MASK], i);
}
__global__ __launch_bounds__(BLOCK) void k_count_fb(const int* __restrict__ x, int n,
                                                    const int* __restrict__ table,
                                                    int* __restrict__ blockSums) {
    int tid = threadIdx.x;
    int base = blockIdx.x * CHUNK + tid * EPT;
    int cnt = 0;
    #pragma unroll
    for (int j = 0; j < EPT; ++j)
        if (base + j < n)
            cnt += (table[(unsigned)x[base + j] & TABLE_MASK] == base + j);
    int tot;
    blk_excl_scan<BLOCK>(cnt, tid, &tot);
    if (tid == 0) blockSums[blockIdx.x] = tot;
}
__global__ __launch_bounds__(BLOCK) void k_rank_fb(const int* __restrict__ x, int n,
                                                   int* __restrict__ table,
                                                   const int* __restrict__ blockSums) {
    int tid = threadIdx.x;
    int base = blockIdx.x * CHUNK + tid * EPT;
    int flags[EPT];
    int cnt = 0;
    #pragma unroll
    for (int j = 0; j < EPT; ++j) {
        flags[j] = 0;
        if (base + j < n)
            flags[j] = (table[(unsigned)x[base + j] & TABLE_MASK] == base + j);
        cnt += flags[j];
    }
    int tot;
    int r = blockSums[blockIdx.x] + blk_excl_scan<BLOCK>(cnt, tid, &tot);
    #pragma unroll
    for (int j = 0; j < EPT; ++j)
        if (flags[j]) table[(unsigned)x[base + j] & TABLE_MASK] = (r++) | RANK_BIT;
}

extern "C" void kernel_launch(void* const* d_in, const int* in_sizes, int n_in,
                              void* d_out, int out_size, void* d_ws, size_t ws_size,
                              hipStream_t stream) {
    const int* x   = (const int*)d_in[0];
    const int* mtp = (const int*)d_in[1];
    int n = in_sizes[0];
    int* out = (int*)d_out;

    int SB  = (n + CHUNK  - 1) / CHUNK;    // 1024-granularity blocks
    int SB2 = (n + CHUNK2 - 1) / CHUNK2;   // 4096-granularity blocks

    auto align16 = [](size_t v) { return (v + 15) & ~(size_t)15; };
    size_t off = 0;
    int* table = (int*)d_ws;                                      off = align16(off + (size_t)TABLE_SIZE * 4);
    unsigned* posArr = (unsigned*)((char*)d_ws + off);            off = align16(off + (size_t)n * 4);
    unsigned short* klArr = (unsigned short*)((char*)d_ws + off); off = align16(off + (size_t)n * 2);
    unsigned char* flag = (unsigned char*)((char*)d_ws + off);    off = align16(off + (size_t)n);
    unsigned* hist = (unsigned*)((char*)d_ws + off);              off = align16(off + (size_t)SB2 * NB * 4);
    unsigned* bucketTot = (unsigned*)((char*)d_ws + off);         off = align16(off + (size_t)NB * 4);
    unsigned* bucketBase = (unsigned*)((char*)d_ws + off);        off = align16(off + (size_t)(NB + 1) * 4);
    int* blockSums = (int*)((char*)d_ws + off);                   off = align16(off + (size_t)SB * 4);
    unsigned long long* bitmask = (unsigned long long*)((char*)d_ws + off);
    off = align16(off + (size_t)SB * (BLOCK / 64) * EPT * 8);

    if (ws_size >= off) {
        k_hist      <<<SB2, BLOCK, 0, stream>>>(x, n, hist);
        k_colscan   <<<NB,  256,   0, stream>>>(hist, SB2, bucketTot);
        k_bucketbase<<<1,   256,   0, stream>>>(bucketTot, bucketBase);
        k_scatter   <<<SB2, BLOCK, 0, stream>>>(x, n, hist, bucketBase, posArr, klArr);
        k_bucket_min<<<NB,  512,   0, stream>>>(posArr, klArr, bucketBase, table, flag);
        k_flags     <<<SB,  BLOCK, 0, stream>>>(flag, n, blockSums, bitmask);
        k_scan      <<<1,   1024,  0, stream>>>(blockSums, SB);
        k_rank      <<<SB,  BLOCK, 0, stream>>>(x, n, table, blockSums, bitmask);
        k_out       <<<SB,  BLOCK, 0, stream>>>(x, n, table, mtp, out);
    } else {
        // minimal-footprint fallback
        size_t foff = align16((size_t)TABLE_SIZE * 4);
        int* bs = (int*)((char*)d_ws + foff);
        hipMemsetAsync(table, 0x7F, (size_t)TABLE_SIZE * 4, stream);
        k_first_idx<<<SB, BLOCK, 0, stream>>>(x, n, table);
        k_count_fb <<<SB, BLOCK, 0, stream>>>(x, n, table, bs);
        k_scan     <<<1, 1024, 0, stream>>>(bs, SB);
        k_rank_fb  <<<SB, BLOCK, 0, stream>>>(x, n, table, bs);
        k_out      <<<SB, BLOCK, 0, stream>>>(x, n, table, mtp, out);
    }
}